// Round 2
// baseline (672.894 us; speedup 1.0000x reference)
//
#include <hip/hip_runtime.h>

#define LEAKY(x) ((x) >= 0.0f ? (x) : 0.01f * (x))

// ---------------- transpose conv_w (32,1024) -> (1024,32) ----------------
__global__ void k_transpose_w(const float* __restrict__ w, float* __restrict__ wT) {
    int idx = blockIdx.x * blockDim.x + threadIdx.x;
    if (idx < 32 * 1024) {
        int o = idx >> 10, c = idx & 1023;
        wT[c * 32 + o] = w[idx];
    }
}

// ---------------- conv (1x1x1 over channels) + bias + leaky_relu ----------------
// grid: 8 b * 196 pos-groups = 1568 blocks, 256 threads.
// Each block: 64 consecutive positions x full 1024 channels.
// Channel dim split 4-way across the block's 4 waves; LDS reduce (pad 33).
__global__ __launch_bounds__(256) void k_conv(const float* __restrict__ video,
                                              const float* __restrict__ wT,
                                              const float* __restrict__ conv_b,
                                              float* __restrict__ attn) {
    __shared__ float lds[256 * 33];
    int blk = blockIdx.x;
    int b = blk / 196, pg = blk % 196;
    int tid = threadIdx.x;
    int lane = tid & 63, wv = tid >> 6;
    int pos = pg * 64 + lane;
    const float* vbase = video + ((size_t)b * 1024 + wv * 256) * 12544 + pos;
    const float* wbase = wT + wv * 256 * 32;
    float acc[32];
#pragma unroll
    for (int o = 0; o < 32; ++o) acc[o] = 0.0f;
    for (int ci = 0; ci < 256; ++ci) {
        float v = vbase[(size_t)ci * 12544];
        const float* wc = wbase + ci * 32;   // wave-uniform -> scalar loads
#pragma unroll
        for (int o = 0; o < 32; ++o) acc[o] = fmaf(v, wc[o], acc[o]);
    }
#pragma unroll
    for (int o = 0; o < 32; ++o) lds[tid * 33 + o] = acc[o];
    __syncthreads();
    // reduce 4 c-groups; 256 threads = 64 pos x 4 o-groups of 8
    int l2 = tid & 63, og = tid >> 6;
    int p2 = pg * 64 + l2;
#pragma unroll
    for (int oo = 0; oo < 8; ++oo) {
        int o = og * 8 + oo;
        float s = lds[(0 * 64 + l2) * 33 + o] + lds[(1 * 64 + l2) * 33 + o]
                + lds[(2 * 64 + l2) * 33 + o] + lds[(3 * 64 + l2) * 33 + o];
        float x = s + conv_b[o];
        attn[((size_t)b * 32 + o) * 12544 + p2] = LEAKY(x);
    }
}

// ---------------- adaptive pool (b,32,64,14,14) -> (b, 32*32*3*3) ----------------
__global__ void k_pool(const float* __restrict__ attn, float* __restrict__ pooled) {
    int idx = blockIdx.x * blockDim.x + threadIdx.x;   // 73728 total
    if (idx >= 8 * 9216) return;
    int j = idx % 3;
    int i = (idx / 3) % 3;
    int a = (idx / 9) % 32;
    int o = (idx / 288) % 32;
    int b = idx / 9216;
    int t0 = a * 2, t1 = a * 2 + 2;                      // 64 -> 32
    int w0 = (i * 14) / 3, w1 = ((i + 1) * 14 + 2) / 3;  // 14 -> 3
    int h0 = (j * 14) / 3, h1 = ((j + 1) * 14 + 2) / 3;
    float s = 0.0f;
    const float* base = attn + ((size_t)b * 32 + o) * 12544;
    for (int t = t0; t < t1; ++t)
        for (int w = w0; w < w1; ++w)
            for (int h = h0; h < h1; ++h)
                s += base[t * 196 + w * 14 + h];
    float cnt = (float)((t1 - t0) * (w1 - w0) * (h1 - h0));
    pooled[idx] = s / cnt;
}

// ---------------- fc11: (8,9216) @ (9216,1024)^T + bias, leaky ----------------
__global__ __launch_bounds__(256) void k_fc11(const float* __restrict__ pooled,
                                              const float* __restrict__ w,
                                              const float* __restrict__ bias,
                                              float* __restrict__ a1) {
    int n = blockIdx.x;          // 0..1023
    int tid = threadIdx.x;
    float acc[8] = {0, 0, 0, 0, 0, 0, 0, 0};
    const float* wr = w + (size_t)n * 9216;
    for (int k = tid; k < 9216; k += 256) {
        float wv = wr[k];
#pragma unroll
        for (int b = 0; b < 8; ++b) acc[b] = fmaf(wv, pooled[b * 9216 + k], acc[b]);
    }
    __shared__ float red[8][256];
#pragma unroll
    for (int b = 0; b < 8; ++b) red[b][tid] = acc[b];
    __syncthreads();
    for (int s2 = 128; s2 > 0; s2 >>= 1) {
        if (tid < s2) {
#pragma unroll
            for (int b = 0; b < 8; ++b) red[b][tid] += red[b][tid + s2];
        }
        __syncthreads();
    }
    if (tid < 8) {
        float x = red[tid][0] + bias[n];
        a1[tid * 1024 + n] = LEAKY(x);
    }
}

// ---------------- fc12 + sigmoid(0.001*x) -> a2 (8,9) ----------------
__global__ __launch_bounds__(64) void k_fc12(const float* __restrict__ a1,
                                             const float* __restrict__ w,
                                             const float* __restrict__ bias,
                                             float* __restrict__ a2) {
    int blk = blockIdx.x;   // 72: b*9 + r
    int b = blk / 9, r = blk % 9;
    int tid = threadIdx.x;
    float s = 0.0f;
    for (int k = tid; k < 1024; k += 64)
        s = fmaf(a1[b * 1024 + k], w[r * 1024 + k], s);
#pragma unroll
    for (int off = 32; off > 0; off >>= 1) s += __shfl_down(s, off);
    if (tid == 0) {
        float x = 0.001f * (s + bias[r]);
        a2[blk] = 1.0f / (1.0f + expf(-x));
    }
}

// ---------------- normalized gaussian filters f (b,3,64,14,14) ----------------
__global__ __launch_bounds__(256) void k_gauss(const float* __restrict__ a2,
                                               const int* __restrict__ length,
                                               float* __restrict__ f) {
    int blk = blockIdx.x;   // 24: b*3 + n
    int b = blk / 3, n = blk % 3;
    float sig = (n == 1) ? 0.0f : 0.5f;        // |SIGMAS[n]|, SIGMAS={-0.5,0,0.5}
    float st2 = expf(14.0f * sig - 3.0f);
    float sx2 = expf(10.0f * sig - 3.0f);
    float inv_t = 1.0f / (st2 + 1e-6f);
    float inv_x = 1.0f / (sx2 + 1e-6f);
    float inv_y = inv_x;
    float lf = (float)length[b];
    float mu_t = (lf - 1.0f) * (a2[b * 9 + n] + 1.0f) * 0.5f;
    float mu_x = 13.0f * (a2[b * 9 + 3 + n] + 1.0f) * 0.5f;
    float mu_y = 13.0f * (a2[b * 9 + 6 + n] + 1.0f) * 0.5f;
    int tid = threadIdx.x;
    float psum = 0.0f;
    for (int it = 0; it < 49; ++it) {
        int pos = it * 256 + tid;
        int t = pos / 196;
        int rem = pos % 196;
        int w = rem / 14, h = rem % 14;
        float dt = (float)t - mu_t, dx = (float)w - mu_x, dy = (float)h - mu_y;
        float e = dt * dt * inv_t + dx * dx * inv_x + dy * dy * inv_y;
        psum += expf(-0.5f * e);
    }
    __shared__ float red[256];
    red[tid] = psum;
    __syncthreads();
    for (int s2 = 128; s2 > 0; s2 >>= 1) {
        if (tid < s2) red[tid] += red[tid + s2];
        __syncthreads();
    }
    float inv_sum = 1.0f / (red[0] + 1e-6f);
    for (int it = 0; it < 49; ++it) {
        int pos = it * 256 + tid;
        int t = pos / 196;
        int rem = pos % 196;
        int w = rem / 14, h = rem % 14;
        float dt = (float)t - mu_t, dx = (float)w - mu_x, dy = (float)h - mu_y;
        float e = dt * dt * inv_t + dx * dx * inv_x + dy * dy * inv_y;
        f[(size_t)blk * 12544 + pos] = expf(-0.5f * e) * inv_sum;
    }
}

// ---------------- final: o[b,c,n] = sum_thw f[b,n,thw] * video[b,c,thw] ----------------
// one block per (b,c); 8192 blocks; float4 loads
__global__ __launch_bounds__(256) void k_final(const float* __restrict__ video,
                                               const float* __restrict__ f,
                                               float* __restrict__ out) {
    int blk = blockIdx.x;   // b*1024 + c
    int b = blk >> 10;
    int tid = threadIdx.x;
    const float4* v4 = (const float4*)(video + (size_t)blk * 12544);
    const float4* f0 = (const float4*)(f + (size_t)b * 3 * 12544);
    const float4* f1 = f0 + 3136;
    const float4* f2 = f0 + 6272;
    float a0 = 0.0f, a1 = 0.0f, a2 = 0.0f;
    for (int idx = tid; idx < 3136; idx += 256) {
        float4 v = v4[idx];
        float4 g0 = f0[idx], g1 = f1[idx], g2 = f2[idx];
        a0 = fmaf(v.x, g0.x, fmaf(v.y, g0.y, fmaf(v.z, g0.z, fmaf(v.w, g0.w, a0))));
        a1 = fmaf(v.x, g1.x, fmaf(v.y, g1.y, fmaf(v.z, g1.z, fmaf(v.w, g1.w, a1))));
        a2 = fmaf(v.x, g2.x, fmaf(v.y, g2.y, fmaf(v.z, g2.z, fmaf(v.w, g2.w, a2))));
    }
    __shared__ float red[3][256];
    red[0][tid] = a0;
    red[1][tid] = a1;
    red[2][tid] = a2;
    __syncthreads();
    for (int s2 = 128; s2 > 0; s2 >>= 1) {
        if (tid < s2) {
            red[0][tid] += red[0][tid + s2];
            red[1][tid] += red[1][tid + s2];
            red[2][tid] += red[2][tid + s2];
        }
        __syncthreads();
    }
    if (tid < 3) {
        int c = blk & 1023;
        out[(size_t)b * 3072 + c * 3 + tid] = red[tid][0];
    }
}

extern "C" void kernel_launch(void* const* d_in, const int* in_sizes, int n_in,
                              void* d_out, int out_size, void* d_ws, size_t ws_size,
                              hipStream_t stream) {
    const float* video  = (const float*)d_in[0];
    const int*   length = (const int*)d_in[1];
    const float* conv_w = (const float*)d_in[2];
    const float* conv_b = (const float*)d_in[3];
    const float* fc11_w = (const float*)d_in[4];
    const float* fc11_b = (const float*)d_in[5];
    const float* fc12_w = (const float*)d_in[6];
    const float* fc12_b = (const float*)d_in[7];
    float* out = (float*)d_out;

    float* ws     = (float*)d_ws;
    float* wT     = ws;                   // 32,768
    float* attn   = wT + 32768;           // 3,211,264
    float* pooled = attn + 3211264;       // 73,728
    float* a1     = pooled + 73728;       // 8,192
    float* a2     = a1 + 8192;            // 72 (padded to 128)
    float* fbuf   = a2 + 128;             // 301,056

    hipLaunchKernelGGL(k_transpose_w, dim3(128),  dim3(256), 0, stream, conv_w, wT);
    hipLaunchKernelGGL(k_conv,        dim3(1568), dim3(256), 0, stream, video, wT, conv_b, attn);
    hipLaunchKernelGGL(k_pool,        dim3(288),  dim3(256), 0, stream, attn, pooled);
    hipLaunchKernelGGL(k_fc11,        dim3(1024), dim3(256), 0, stream, pooled, fc11_w, fc11_b, a1);
    hipLaunchKernelGGL(k_fc12,        dim3(72),   dim3(64),  0, stream, a1, fc12_w, fc12_b, a2);
    hipLaunchKernelGGL(k_gauss,       dim3(24),   dim3(256), 0, stream, a2, length, fbuf);
    hipLaunchKernelGGL(k_final,       dim3(8192), dim3(256), 0, stream, video, fbuf, out);
}

// Round 3
// 295.159 us; speedup vs baseline: 2.2798x; 2.2798x over previous
//
#include <hip/hip_runtime.h>

#define LEAKY(x) ((x) >= 0.0f ? (x) : 0.01f * (x))

// ---------------- transpose conv_w (32,1024) -> (1024,32) ----------------
__global__ void k_transpose_w(const float* __restrict__ w, float* __restrict__ wT) {
    int idx = blockIdx.x * blockDim.x + threadIdx.x;
    if (idx < 32 * 1024) {
        int o = idx >> 10, c = idx & 1023;
        wT[c * 32 + o] = w[idx];
    }
}

// ---------------- conv partials: channel-split 2-way, depth-8 prefetch ----------------
// grid: 8b * 2cs * 49pg = 784 blocks, 256 threads, one position per thread.
// partial[(b*2+cs)][o][pos] = sum_{c in cs half} video[b,c,pos] * w[o,c]
__global__ __launch_bounds__(256) void k_conv_part(const float* __restrict__ video,
                                                   const float* __restrict__ wT,
                                                   float* __restrict__ partial) {
    int blk = blockIdx.x;            // bcs*49 + pg
    int pg  = blk % 49;
    int bcs = blk / 49;              // b*2+cs, 0..15
    int cs  = bcs & 1;
    int b   = bcs >> 1;
    int pos = pg * 256 + threadIdx.x;
    const float* vp = video + ((size_t)(b * 1024 + cs * 512)) * 12544 + pos;
    const float* wp = wT + cs * 512 * 32;
    float acc[32];
#pragma unroll
    for (int o = 0; o < 32; ++o) acc[o] = 0.0f;
    float pre[8];
#pragma unroll
    for (int i = 0; i < 8; ++i) pre[i] = vp[(size_t)i * 12544];
    for (int c0 = 0; c0 < 512; c0 += 8) {
        float cur[8];
#pragma unroll
        for (int i = 0; i < 8; ++i) cur[i] = pre[i];
        if (c0 + 8 < 512) {
#pragma unroll
            for (int i = 0; i < 8; ++i) pre[i] = vp[(size_t)(c0 + 8 + i) * 12544];
        }
#pragma unroll
        for (int i = 0; i < 8; ++i) {
            const float* wc = wp + (c0 + i) * 32;   // wave-uniform -> scalar loads
#pragma unroll
            for (int o = 0; o < 32; ++o) acc[o] = fmaf(cur[i], wc[o], acc[o]);
        }
    }
    float* pp = partial + (size_t)bcs * 32 * 12544 + pos;
#pragma unroll
    for (int o = 0; o < 32; ++o) pp[(size_t)o * 12544] = acc[o];
}

// ---------------- reduce partials + bias + leaky -> attn (b,32,12544) ----------------
__global__ __launch_bounds__(256) void k_conv_reduce(const float* __restrict__ partial,
                                                     const float* __restrict__ conv_b,
                                                     float* __restrict__ attn) {
    int idx = blockIdx.x * 256 + threadIdx.x;   // over 8*32*3136 float4 groups
    if (idx >= 8 * 32 * 3136) return;
    int p4 = idx % 3136;
    int o  = (idx / 3136) % 32;
    int b  = idx / (3136 * 32);
    float4 x0 = ((const float4*)(partial + ((size_t)(b * 2 + 0) * 32 + o) * 12544))[p4];
    float4 x1 = ((const float4*)(partial + ((size_t)(b * 2 + 1) * 32 + o) * 12544))[p4];
    float bo = conv_b[o];
    float4 r;
    r.x = LEAKY(x0.x + x1.x + bo);
    r.y = LEAKY(x0.y + x1.y + bo);
    r.z = LEAKY(x0.z + x1.z + bo);
    r.w = LEAKY(x0.w + x1.w + bo);
    ((float4*)(attn + ((size_t)b * 32 + o) * 12544))[p4] = r;
}

// ---------------- adaptive pool (b,32,64,14,14) -> (b, 32*32*3*3) ----------------
__global__ void k_pool(const float* __restrict__ attn, float* __restrict__ pooled) {
    int idx = blockIdx.x * blockDim.x + threadIdx.x;   // 73728 total
    if (idx >= 8 * 9216) return;
    int j = idx % 3;
    int i = (idx / 3) % 3;
    int a = (idx / 9) % 32;
    int o = (idx / 288) % 32;
    int b = idx / 9216;
    int t0 = a * 2, t1 = a * 2 + 2;                      // 64 -> 32
    int w0 = (i * 14) / 3, w1 = ((i + 1) * 14 + 2) / 3;  // 14 -> 3
    int h0 = (j * 14) / 3, h1 = ((j + 1) * 14 + 2) / 3;
    float s = 0.0f;
    const float* base = attn + ((size_t)b * 32 + o) * 12544;
    for (int t = t0; t < t1; ++t)
        for (int w = w0; w < w1; ++w)
            for (int h = h0; h < h1; ++h)
                s += base[t * 196 + w * 14 + h];
    float cnt = (float)((t1 - t0) * (w1 - w0) * (h1 - h0));
    pooled[idx] = s / cnt;
}

// ---------------- fc11: (8,9216) @ (9216,1024)^T + bias, leaky ----------------
__global__ __launch_bounds__(256) void k_fc11(const float* __restrict__ pooled,
                                              const float* __restrict__ w,
                                              const float* __restrict__ bias,
                                              float* __restrict__ a1) {
    int n = blockIdx.x;          // 0..1023
    int tid = threadIdx.x;
    float acc[8] = {0, 0, 0, 0, 0, 0, 0, 0};
    const float* wr = w + (size_t)n * 9216;
    for (int k = tid; k < 9216; k += 256) {
        float wv = wr[k];
#pragma unroll
        for (int b = 0; b < 8; ++b) acc[b] = fmaf(wv, pooled[b * 9216 + k], acc[b]);
    }
    __shared__ float red[8][256];
#pragma unroll
    for (int b = 0; b < 8; ++b) red[b][tid] = acc[b];
    __syncthreads();
    for (int s2 = 128; s2 > 0; s2 >>= 1) {
        if (tid < s2) {
#pragma unroll
            for (int b = 0; b < 8; ++b) red[b][tid] += red[b][tid + s2];
        }
        __syncthreads();
    }
    if (tid < 8) {
        float x = red[tid][0] + bias[n];
        a1[tid * 1024 + n] = LEAKY(x);
    }
}

// ---------------- fc12 + sigmoid(0.001*x) -> a2 (8,9) ----------------
__global__ __launch_bounds__(64) void k_fc12(const float* __restrict__ a1,
                                             const float* __restrict__ w,
                                             const float* __restrict__ bias,
                                             float* __restrict__ a2) {
    int blk = blockIdx.x;   // 72: b*9 + r
    int b = blk / 9, r = blk % 9;
    int tid = threadIdx.x;
    float s = 0.0f;
    for (int k = tid; k < 1024; k += 64)
        s = fmaf(a1[b * 1024 + k], w[r * 1024 + k], s);
#pragma unroll
    for (int off = 32; off > 0; off >>= 1) s += __shfl_down(s, off);
    if (tid == 0) {
        float x = 0.001f * (s + bias[r]);
        a2[blk] = 1.0f / (1.0f + expf(-x));
    }
}

// ---------------- normalized gaussian filters f (b,3,64,14,14) ----------------
__global__ __launch_bounds__(256) void k_gauss(const float* __restrict__ a2,
                                               const int* __restrict__ length,
                                               float* __restrict__ f) {
    int blk = blockIdx.x;   // 24: b*3 + n
    int b = blk / 3, n = blk % 3;
    float sig = (n == 1) ? 0.0f : 0.5f;        // |SIGMAS[n]|, SIGMAS={-0.5,0,0.5}
    float st2 = expf(14.0f * sig - 3.0f);
    float sx2 = expf(10.0f * sig - 3.0f);
    float inv_t = 1.0f / (st2 + 1e-6f);
    float inv_x = 1.0f / (sx2 + 1e-6f);
    float inv_y = inv_x;
    float lf = (float)length[b];
    float mu_t = (lf - 1.0f) * (a2[b * 9 + n] + 1.0f) * 0.5f;
    float mu_x = 13.0f * (a2[b * 9 + 3 + n] + 1.0f) * 0.5f;
    float mu_y = 13.0f * (a2[b * 9 + 6 + n] + 1.0f) * 0.5f;
    int tid = threadIdx.x;
    float psum = 0.0f;
    for (int it = 0; it < 49; ++it) {
        int pos = it * 256 + tid;
        int t = pos / 196;
        int rem = pos % 196;
        int w = rem / 14, h = rem % 14;
        float dt = (float)t - mu_t, dx = (float)w - mu_x, dy = (float)h - mu_y;
        float e = dt * dt * inv_t + dx * dx * inv_x + dy * dy * inv_y;
        psum += expf(-0.5f * e);
    }
    __shared__ float red[256];
    red[tid] = psum;
    __syncthreads();
    for (int s2 = 128; s2 > 0; s2 >>= 1) {
        if (tid < s2) red[tid] += red[tid + s2];
        __syncthreads();
    }
    float inv_sum = 1.0f / (red[0] + 1e-6f);
    for (int it = 0; it < 49; ++it) {
        int pos = it * 256 + tid;
        int t = pos / 196;
        int rem = pos % 196;
        int w = rem / 14, h = rem % 14;
        float dt = (float)t - mu_t, dx = (float)w - mu_x, dy = (float)h - mu_y;
        float e = dt * dt * inv_t + dx * dx * inv_x + dy * dy * inv_y;
        f[(size_t)blk * 12544 + pos] = expf(-0.5f * e) * inv_sum;
    }
}

// ---------------- final: o[b,c,n] = sum_thw f[b,n,thw] * video[b,c,thw] ----------------
// one block per (b,c); 8192 blocks; float4 loads
__global__ __launch_bounds__(256) void k_final(const float* __restrict__ video,
                                               const float* __restrict__ f,
                                               float* __restrict__ out) {
    int blk = blockIdx.x;   // b*1024 + c
    int b = blk >> 10;
    int tid = threadIdx.x;
    const float4* v4 = (const float4*)(video + (size_t)blk * 12544);
    const float4* f0 = (const float4*)(f + (size_t)b * 3 * 12544);
    const float4* f1 = f0 + 3136;
    const float4* f2 = f0 + 6272;
    float a0 = 0.0f, a1 = 0.0f, a2 = 0.0f;
    for (int idx = tid; idx < 3136; idx += 256) {
        float4 v = v4[idx];
        float4 g0 = f0[idx], g1 = f1[idx], g2 = f2[idx];
        a0 = fmaf(v.x, g0.x, fmaf(v.y, g0.y, fmaf(v.z, g0.z, fmaf(v.w, g0.w, a0))));
        a1 = fmaf(v.x, g1.x, fmaf(v.y, g1.y, fmaf(v.z, g1.z, fmaf(v.w, g1.w, a1))));
        a2 = fmaf(v.x, g2.x, fmaf(v.y, g2.y, fmaf(v.z, g2.z, fmaf(v.w, g2.w, a2))));
    }
    __shared__ float red[3][256];
    red[0][tid] = a0;
    red[1][tid] = a1;
    red[2][tid] = a2;
    __syncthreads();
    for (int s2 = 128; s2 > 0; s2 >>= 1) {
        if (tid < s2) {
            red[0][tid] += red[0][tid + s2];
            red[1][tid] += red[1][tid + s2];
            red[2][tid] += red[2][tid + s2];
        }
        __syncthreads();
    }
    if (tid < 3) {
        int c = blk & 1023;
        out[(size_t)b * 3072 + c * 3 + tid] = red[tid][0];
    }
}

extern "C" void kernel_launch(void* const* d_in, const int* in_sizes, int n_in,
                              void* d_out, int out_size, void* d_ws, size_t ws_size,
                              hipStream_t stream) {
    const float* video  = (const float*)d_in[0];
    const int*   length = (const int*)d_in[1];
    const float* conv_w = (const float*)d_in[2];
    const float* conv_b = (const float*)d_in[3];
    const float* fc11_w = (const float*)d_in[4];
    const float* fc11_b = (const float*)d_in[5];
    const float* fc12_w = (const float*)d_in[6];
    const float* fc12_b = (const float*)d_in[7];
    float* out = (float*)d_out;

    float* ws      = (float*)d_ws;
    float* wT      = ws;                    // 32,768
    float* attn    = wT + 32768;            // 3,211,264
    float* partial = attn + 3211264;        // 6,422,528 (16 * 32 * 12544)
    float* pooled  = partial + 6422528;     // 73,728
    float* a1      = pooled + 73728;        // 8,192
    float* a2      = a1 + 8192;             // 72 (padded to 128)
    float* fbuf    = a2 + 128;              // 301,056

    hipLaunchKernelGGL(k_transpose_w, dim3(128),  dim3(256), 0, stream, conv_w, wT);
    hipLaunchKernelGGL(k_conv_part,   dim3(784),  dim3(256), 0, stream, video, wT, partial);
    hipLaunchKernelGGL(k_conv_reduce, dim3(3136), dim3(256), 0, stream, partial, conv_b, attn);
    hipLaunchKernelGGL(k_pool,        dim3(288),  dim3(256), 0, stream, attn, pooled);
    hipLaunchKernelGGL(k_fc11,        dim3(1024), dim3(256), 0, stream, pooled, fc11_w, fc11_b, a1);
    hipLaunchKernelGGL(k_fc12,        dim3(72),   dim3(64),  0, stream, a1, fc12_w, fc12_b, a2);
    hipLaunchKernelGGL(k_gauss,       dim3(24),   dim3(256), 0, stream, a2, length, fbuf);
    hipLaunchKernelGGL(k_final,       dim3(8192), dim3(256), 0, stream, video, fbuf, out);
}